// Round 4
// baseline (163.172 us; speedup 1.0000x reference)
//
#include <hip/hip_runtime.h>
#include <math.h>

#define TPB 256
constexpr int kS = 7;
constexpr int kB = 2;
constexpr int kC = 20;
constexpr int kT = 32;
constexpr int kCH = kB * 5 + kC;      // 30 channels
constexpr int kCells = kS * kS;       // 49
constexpr int kImgF = kCells * kCH;   // 1470 floats per image
constexpr int IMGS = 8;               // images per block -> 2048 blocks, all 256 threads own a target

// Block-wide sum reduction (result valid on thread 0 only).
__device__ __forceinline__ float block_reduce(float v, float* red) {
    #pragma unroll
    for (int off = 32; off > 0; off >>= 1)
        v += __shfl_down(v, off, 64);
    const int lane = threadIdx.x & 63;
    const int wave = threadIdx.x >> 6;
    if (lane == 0) red[wave] = v;
    __syncthreads();
    float s = 0.0f;
    if (threadIdx.x == 0) {
        #pragma unroll
        for (int w = 0; w < TPB / 64; w++) s += red[w];
    }
    return s;
}

// Stage 1, LDS-free. Phase 1: register-stream the block's 8 images (float4,
// coalesced) accumulating the noobj conf^2 term; nothing is staged to LDS
// (R3 post-mortem: we wrote 23.5KB/block to LDS but consumed <8% of it).
// Phase 2 (no barrier needed -- data comes from global, L1/L2-warm from
// phase 1): one thread per target gathers its cell's 30 floats and computes
// box/obj/class terms. One partial per block; stage 2 reduces.
__global__ __launch_bounds__(TPB) void yolo_stage1(
    const float* __restrict__ outputs,
    const float4* __restrict__ tboxes,
    const int* __restrict__ tlabels,
    float* __restrict__ blocksums,
    int n)
{
    __shared__ float red[TPB / 64];
    const int tid = threadIdx.x;
    const int img0 = blockIdx.x * IMGS;
    const int nimg = min(IMGS, n - img0);

    float local = 0.0f;
    const float kno = 0.5f / (float)(2 * kCells);   // LAMBDA_NOOBJ / 98

    // ---- Prefetch this thread's target (overlaps the streaming loads) ----
    const bool has_tgt = tid < nimg * kT;
    float4 tb = make_float4(0.f, 0.f, 0.f, 0.f);
    int lab = 0;
    if (has_tgt) {
        tb = tboxes[(size_t)img0 * kT + tid];
        lab = tlabels[(size_t)img0 * kT + tid];
    }

    // ---- Phase 1: stream, accumulate noobj conf^2 in registers ----
    if (nimg == IMGS) {
        // img0*kImgF floats = blockIdx*8*5880 B, 16B-aligned; 8*1470 % 30 == 0
        const float4* src = reinterpret_cast<const float4*>(outputs + (size_t)img0 * kImgF);
        constexpr int NV4 = IMGS * kImgF / 4;       // 2940
        constexpr int FULL = NV4 / TPB;             // 11 full rounds (2816)
        // channel of v.x for float4 idx is (4*idx)%30; step per round: (4*TPB)%30 == 4
        int base = (4 * tid) % 30;
        #pragma unroll
        for (int i = 0; i < FULL; i++) {
            const float4 v = src[tid + i * TPB];
            if (base == 8)      local += kno * (v.x * v.x + v.y * v.y);
            else if (base == 6) local += kno * (v.z * v.z + v.w * v.w);
            base += 4; if (base >= 30) base -= 30;
        }
        const int idx = tid + FULL * TPB;           // remainder: 124 float4s
        if (idx < NV4) {
            const float4 v = src[idx];
            if (base == 8)      local += kno * (v.x * v.x + v.y * v.y);
            else if (base == 6) local += kno * (v.z * v.z + v.w * v.w);
        }
    } else {
        // tail (never hit at N=16384): scalar
        const float* srcf = outputs + (size_t)img0 * kImgF;
        const int tot = nimg * kImgF;
        for (int i = tid; i < tot; i += TPB) {
            const float v = srcf[i];
            const int ch = i % kCH;
            if (ch == 8 || ch == 9) local += kno * v * v;
        }
    }

    // ---- Phase 2: per-target terms, gathered directly from global ----
    if (has_tgt) {
        const int sub = tid >> 5;                   // image within block
        const float cellf = 1.0f / 7.0f;
        const float tx = tb.x, ty = tb.y, tw = tb.z, th = tb.w;

        int gxi = (int)(tx / cellf); gxi = min(max(gxi, 0), kS - 1);
        int gyi = (int)(ty / cellf); gyi = min(max(gyi, 0), kS - 1);
        const float ox = (tx - (float)gxi * cellf) / cellf;
        const float oy = (ty - (float)gyi * cellf) / cellf;
        const float* __restrict__ cellp =
            outputs + (size_t)(img0 + sub) * kImgF + (gyi * kS + gxi) * kCH;

        const float t_x1 = tx - tw * 0.5f, t_x2 = tx + tw * 0.5f;
        const float t_y1 = ty - th * 0.5f, t_y2 = ty + th * 0.5f;
        const float tarea = tw * th;
        float ious[2], bxs[2], bys[2], bws[2], bhs[2];
        #pragma unroll
        for (int b = 0; b < 2; b++) {
            const float x = cellp[4 * b + 0], y = cellp[4 * b + 1];
            const float w = cellp[4 * b + 2], h = cellp[4 * b + 3];
            const float px = (x + (float)gxi) * cellf;
            const float py = (y + (float)gyi) * cellf;
            const float x21 = px - w * 0.5f, x22 = px + w * 0.5f;
            const float y21 = py - h * 0.5f, y22 = py + h * 0.5f;
            const float iw = fmaxf(fminf(t_x2, x22) - fmaxf(t_x1, x21), 0.0f);
            const float ih = fmaxf(fminf(t_y2, y22) - fmaxf(t_y1, y21), 0.0f);
            const float inter = iw * ih;
            const float uni = tarea + w * h - inter;
            ious[b] = inter / fmaxf(uni, 1e-6f);
            bxs[b] = px; bys[b] = py; bws[b] = w; bhs[b] = h;
        }
        // jnp.argmax picks the FIRST max on ties -> strict '>' for index 1
        const int best = (ious[1] > ious[0]) ? 1 : 0;

        const float pw = fmaxf(bws[best], 1e-6f), ph = fmaxf(bhs[best], 1e-6f);
        const float twc = fmaxf(tw, 1e-6f), thc = fmaxf(th, 1e-6f);
        const float dx = bxs[best] - ox, dy = bys[best] - oy;
        const float dw = sqrtf(pw) - sqrtf(twc), dh = sqrtf(ph) - sqrtf(thc);
        const float box_loss = dx * dx + dy * dy + dw * dw + dh * dh;

        const float dconf = cellp[8 + best] - 1.0f;
        const float obj_loss = dconf * dconf;

        // class loss: mean over C of (softmax - onehot)^2
        float cls[kC];
        #pragma unroll
        for (int c = 0; c < kC; c++) cls[c] = cellp[10 + c];
        float m = cls[0];
        #pragma unroll
        for (int c = 1; c < kC; c++) m = fmaxf(m, cls[c]);
        float ssum = 0.0f;
        #pragma unroll
        for (int c = 0; c < kC; c++) { cls[c] = __expf(cls[c] - m); ssum += cls[c]; }
        const float inv = 1.0f / ssum;
        float cl = 0.0f;
        #pragma unroll
        for (int c = 0; c < kC; c++) {
            const float d = cls[c] * inv - (c == lab ? 1.0f : 0.0f);
            cl += d * d;
        }

        local += 5.0f * box_loss + obj_loss + cl * (1.0f / (float)kC);
    }

    const float bsum = block_reduce(local, red);
    if (tid == 0) blocksums[blockIdx.x] = bsum;
}

// Stage 2: reduce per-block partials, write mean.
__global__ __launch_bounds__(TPB) void yolo_stage2(
    const float* __restrict__ blocksums, int nblocks, float invn,
    float* __restrict__ out)
{
    __shared__ float red[TPB / 64];
    float local = 0.0f;
    for (int i = threadIdx.x; i < nblocks; i += TPB) local += blocksums[i];
    const float s = block_reduce(local, red);
    if (threadIdx.x == 0) out[0] = s * invn;
}

extern "C" void kernel_launch(void* const* d_in, const int* in_sizes, int n_in,
                              void* d_out, int out_size, void* d_ws, size_t ws_size,
                              hipStream_t stream)
{
    const float* outputs = (const float*)d_in[0];
    const float4* tboxes = (const float4*)d_in[1];
    const int* tlabels = (const int*)d_in[2];
    float* out = (float*)d_out;
    float* blocksums = (float*)d_ws;

    const int n = in_sizes[0] / kImgF;                 // 16384
    const int nblocks = (n + IMGS - 1) / IMGS;         // 2048

    yolo_stage1<<<nblocks, TPB, 0, stream>>>(outputs, tboxes, tlabels, blocksums, n);
    yolo_stage2<<<1, TPB, 0, stream>>>(blocksums, nblocks, 1.0f / (float)n, out);
}

// Round 5
// 153.424 us; speedup vs baseline: 1.0635x; 1.0635x over previous
//
#include <hip/hip_runtime.h>
#include <math.h>

#define TPB 256
constexpr int kS = 7;
constexpr int kB = 2;
constexpr int kC = 20;
constexpr int kT = 32;
constexpr int kCH = kB * 5 + kC;      // 30 channels
constexpr int kCells = kS * kS;       // 49
constexpr int kImgF = kCells * kCH;   // 1470 floats per image
constexpr int IMGS = 4;               // 4 imgs/block -> 128 targets -> 2 lanes/target

// Block-wide sum reduction (result valid on thread 0 only).
__device__ __forceinline__ float block_reduce(float v, float* red) {
    #pragma unroll
    for (int off = 32; off > 0; off >>= 1)
        v += __shfl_down(v, off, 64);
    const int lane = threadIdx.x & 63;
    const int wave = threadIdx.x >> 6;
    if (lane == 0) red[wave] = v;
    __syncthreads();
    float s = 0.0f;
    if (threadIdx.x == 0) {
        #pragma unroll
        for (int w = 0; w < TPB / 64; w++) s += red[w];
    }
    return s;
}

// Stage 1, LDS-free. Phase 1: register-batched stream of the block's 4 images
// (all float4 loads issued before any consume -> full MLP). Phase 2: TWO lanes
// per target; each lane loads its own box (float2) + half the classes, IoU and
// softmax halves combined with shfl_xor. Halves divergent-gather address work
// vs one-thread-per-target. One partial per block.
__global__ __launch_bounds__(TPB) void yolo_stage1(
    const float* __restrict__ outputs,
    const float4* __restrict__ tboxes,
    const int* __restrict__ tlabels,
    float* __restrict__ blocksums,
    int n)
{
    __shared__ float red[TPB / 64];
    const int tid = threadIdx.x;
    const int img0 = blockIdx.x * IMGS;
    const int nimg = min(IMGS, n - img0);

    float local = 0.0f;
    const float kno = 0.5f / (float)(2 * kCells);   // LAMBDA_NOOBJ / 98

    // ---- pair decomposition for phase 2 ----
    const int pair = tid >> 1;        // target slot 0..127
    const int b = tid & 1;            // which predicted box this lane owns
    const bool has_tgt = pair < nimg * kT;
    float4 tb = make_float4(0.f, 0.f, 0.f, 0.f);
    int lab = 0;
    if (has_tgt) {                    // both lanes of a pair load the same 16B/4B
        tb = tboxes[(size_t)img0 * kT + pair];
        lab = tlabels[(size_t)img0 * kT + pair];
    }

    // ---- Phase 1: stream block's images, noobj conf^2 from registers ----
    if (nimg == IMGS) {
        const float4* src = reinterpret_cast<const float4*>(outputs + (size_t)img0 * kImgF);
        constexpr int NV4 = IMGS * kImgF / 4;       // 1470
        constexpr int FULL = NV4 / TPB;             // 5 full rounds (1280)
        float4 vv[FULL];
        #pragma unroll
        for (int i = 0; i < FULL; i++) vv[i] = src[tid + i * TPB];   // all in flight
        const int tidx = tid + FULL * TPB;          // remainder: 190 float4s
        float4 vt = make_float4(0.f, 0.f, 0.f, 0.f);
        const bool tok = tidx < NV4;
        if (tok) vt = src[tidx];

        // channel of v.x for float4 idx is (4*idx)%30; step per round (4*TPB)%30==4
        int base = (4 * tid) % 30;
        #pragma unroll
        for (int i = 0; i < FULL; i++) {
            const float4 v = vv[i];
            if (base == 8)      local += kno * (v.x * v.x + v.y * v.y);
            else if (base == 6) local += kno * (v.z * v.z + v.w * v.w);
            base += 4; if (base >= 30) base -= 30;
        }
        if (tok) {
            if (base == 8)      local += kno * (vt.x * vt.x + vt.y * vt.y);
            else if (base == 6) local += kno * (vt.z * vt.z + vt.w * vt.w);
        }
    } else {
        // tail (never hit at N=16384): scalar
        const float* srcf = outputs + (size_t)img0 * kImgF;
        const int tot = nimg * kImgF;
        for (int i = tid; i < tot; i += TPB) {
            const float v = srcf[i];
            const int ch = i % kCH;
            if (ch == 8 || ch == 9) local += kno * v * v;
        }
    }

    // ---- Phase 2: per-target terms, 2 lanes/target, float2 gathers ----
    if (has_tgt) {
        const int sub = pair >> 5;                  // image within block
        const float cellf = 1.0f / 7.0f;
        const float tx = tb.x, ty = tb.y, tw = tb.z, th = tb.w;

        int gxi = (int)(tx / cellf); gxi = min(max(gxi, 0), kS - 1);
        int gyi = (int)(ty / cellf); gyi = min(max(gyi, 0), kS - 1);
        const float ox = (tx - (float)gxi * cellf) / cellf;
        const float oy = (ty - (float)gyi * cellf) / cellf;
        const float2* __restrict__ cell2 = reinterpret_cast<const float2*>(
            outputs + (size_t)(img0 + sub) * kImgF + (gyi * kS + gxi) * kCH);

        // my box: channels 4b..4b+3 (float2-aligned), conf pair at ch 8
        const float2 xy = cell2[2 * b + 0];
        const float2 wh = cell2[2 * b + 1];
        const float2 cf = cell2[4];
        // my class half: channels 10+10b .. 19+10b (5 float2s)
        float cls[10];
        #pragma unroll
        for (int j = 0; j < 5; j++) {
            const float2 c2 = cell2[5 + 5 * b + j];
            cls[2 * j] = c2.x; cls[2 * j + 1] = c2.y;
        }

        // IoU of target vs my box (global coords)
        const float t_x1 = tx - tw * 0.5f, t_x2 = tx + tw * 0.5f;
        const float t_y1 = ty - th * 0.5f, t_y2 = ty + th * 0.5f;
        const float px = (xy.x + (float)gxi) * cellf;
        const float py = (xy.y + (float)gyi) * cellf;
        const float x21 = px - wh.x * 0.5f, x22 = px + wh.x * 0.5f;
        const float y21 = py - wh.y * 0.5f, y22 = py + wh.y * 0.5f;
        const float iw = fmaxf(fminf(t_x2, x22) - fmaxf(t_x1, x21), 0.0f);
        const float ih = fmaxf(fminf(t_y2, y22) - fmaxf(t_y1, y21), 0.0f);
        const float inter = iw * ih;
        const float uni = tw * th + wh.x * wh.y - inter;
        const float iou_mine = inter / fmaxf(uni, 1e-6f);
        const float iou_other = __shfl_xor(iou_mine, 1, 64);
        const float iou0 = b ? iou_other : iou_mine;
        const float iou1 = b ? iou_mine : iou_other;
        // jnp.argmax picks the FIRST max on ties -> strict '>' for index 1
        const int best = (iou1 > iou0) ? 1 : 0;

        if (b == best) {   // exactly one lane of the pair adds box+obj terms
            const float pw = fmaxf(wh.x, 1e-6f), ph = fmaxf(wh.y, 1e-6f);
            const float twc = fmaxf(tw, 1e-6f), thc = fmaxf(th, 1e-6f);
            const float dx = px - ox, dy = py - oy;
            const float dws = sqrtf(pw) - sqrtf(twc), dhs = sqrtf(ph) - sqrtf(thc);
            const float box_loss = dx * dx + dy * dy + dws * dws + dhs * dhs;
            const float dconf = (b ? cf.y : cf.x) - 1.0f;
            local += 5.0f * box_loss + dconf * dconf;
        }

        // class loss half: softmax max & denom combined exactly across the pair
        float mh = cls[0];
        #pragma unroll
        for (int j = 1; j < 10; j++) mh = fmaxf(mh, cls[j]);
        const float m = fmaxf(mh, __shfl_xor(mh, 1, 64));
        float sh = 0.0f;
        #pragma unroll
        for (int j = 0; j < 10; j++) { cls[j] = __expf(cls[j] - m); sh += cls[j]; }
        const float ssum = sh + __shfl_xor(sh, 1, 64);
        const float inv = 1.0f / ssum;
        float cl = 0.0f;
        const int labh = lab - 10 * b;              // my half covers classes 10b..10b+9
        #pragma unroll
        for (int j = 0; j < 10; j++) {
            const float d = cls[j] * inv - (j == labh ? 1.0f : 0.0f);
            cl += d * d;
        }
        local += cl * (1.0f / (float)kC);           // halves sum via block reduce
    }

    const float bsum = block_reduce(local, red);
    if (tid == 0) blocksums[blockIdx.x] = bsum;
}

// Stage 2: reduce per-block partials, write mean.
__global__ __launch_bounds__(TPB) void yolo_stage2(
    const float* __restrict__ blocksums, int nblocks, float invn,
    float* __restrict__ out)
{
    __shared__ float red[TPB / 64];
    float local = 0.0f;
    for (int i = threadIdx.x; i < nblocks; i += TPB) local += blocksums[i];
    const float s = block_reduce(local, red);
    if (threadIdx.x == 0) out[0] = s * invn;
}

extern "C" void kernel_launch(void* const* d_in, const int* in_sizes, int n_in,
                              void* d_out, int out_size, void* d_ws, size_t ws_size,
                              hipStream_t stream)
{
    const float* outputs = (const float*)d_in[0];
    const float4* tboxes = (const float4*)d_in[1];
    const int* tlabels = (const int*)d_in[2];
    float* out = (float*)d_out;
    float* blocksums = (float*)d_ws;

    const int n = in_sizes[0] / kImgF;                 // 16384
    const int nblocks = (n + IMGS - 1) / IMGS;         // 4096

    yolo_stage1<<<nblocks, TPB, 0, stream>>>(outputs, tboxes, tlabels, blocksums, n);
    yolo_stage2<<<1, TPB, 0, stream>>>(blocksums, nblocks, 1.0f / (float)n, out);
}